// Round 5
// baseline (134.699 us; speedup 1.0000x reference)
//
#include <hip/hip_runtime.h>

#define EDGE 4096
#define NPIX (EDGE * EDGE)
#define TILES_X 64
#define NTILES (TILES_X * TILES_X)   // 4096 tiles of 64x64
#define SLOTS 2048                   // max 4-connected components in 64x64

// ================= global forest (compact node space) =================
// Invariant: L[n] <= n, pointers only decrease (atomicMin) -> root = min of
// its tree -> every atomicMin capture (old==hi) merges two DISTINCT sets.
// n_components = n_initial_roots - n_captures, exactly.
static __device__ __forceinline__ int g_load(int* L, int i) {
    return __hip_atomic_load(&L[i], __ATOMIC_RELAXED, __HIP_MEMORY_SCOPE_AGENT);
}
static __device__ __forceinline__ int g_find(int* L, int i) {
    int p = g_load(L, i);
    while (p != i) { i = p; p = g_load(L, i); }
    return i;
}
static __device__ int g_unite(int* L, int a, int b) {   // returns captures (0/1)
    while (true) {
        a = g_find(L, a); b = g_find(L, b);
        if (a == b) return 0;
        const int lo = a < b ? a : b;
        const int hi = a ^ b ^ lo;
        const int old = atomicMin(&L[hi], lo);
        if (old == hi) return 1;   // hi was root: one set merged away
        a = lo; b = old;
    }
}

// ================= LDS union-find =================
static __device__ __forceinline__ int l_load(int* L, int i) {
    return __hip_atomic_load(&L[i], __ATOMIC_RELAXED, __HIP_MEMORY_SCOPE_WORKGROUP);
}
static __device__ __forceinline__ int l_find(int* L, int i) {
    int p = l_load(L, i);
    while (p != i) { i = p; p = l_load(L, i); }
    return i;
}
static __device__ void l_unite(int* L, int a, int b) {
    while (true) {
        a = l_find(L, a); b = l_find(L, b);
        if (a == b) return;
        const int lo = a < b ? a : b;
        const int hi = a ^ b ^ lo;
        const int old = atomicMin(&L[hi], lo);
        if (old == hi) return;
        a = lo; b = old;
    }
}
static __device__ __forceinline__ int l_find_plain(const int* L, int i) {
    int p = L[i];
    while (p != i) { i = p; p = L[i]; }
    return i;
}

// ================= fused pass A+B: mask + tanh + tile CCL =================
__global__ __launch_bounds__(256) void k_tile(const float* __restrict__ x,
                                              int* __restrict__ G,
                                              int* __restrict__ topM, int* __restrict__ botM,
                                              int* __restrict__ leftM, int* __restrict__ rightM,
                                              int* __restrict__ rootsArr,
                                              double* __restrict__ partials,
                                              unsigned int* __restrict__ doneCnt) {
    __shared__ unsigned long long mrow[64];
    __shared__ unsigned int mpart[64][4];
    __shared__ int lab[4096];
    __shared__ int scanb[256];
    __shared__ double wsum[4];
    const int t = threadIdx.x;
    const int tile = blockIdx.x;
    const int tr = tile >> 6, tc = tile & 63;

    if (tile == 0 && t == 0) *doneCnt = 0;   // reset for k_xmerge (stream-ordered)

    // --- load own 16 pixels (row r, 16-px quarter qd), mask + tanh sum ---
    const int r = t >> 2, qd = t & 3;
    const float4* xp = reinterpret_cast<const float4*>(
        x + ((size_t)((tr << 6) | r) << 12) + (tc << 6) + (qd << 4));
    unsigned int m16 = 0;
    double s = 0.0;
    #pragma unroll
    for (int k = 0; k < 4; ++k) {
        const float4 a = xp[k];
        const float vv[4] = {a.x, a.y, a.z, a.w};
        #pragma unroll
        for (int j = 0; j < 4; ++j) {
            const float v = vv[j];
            if (v > 0.0f) {                       // tanh(x)>0 <=> x>0
                m16 |= 1u << (k * 4 + j);
                const float e = __expf(2.0f * v); // tanh = 1 - 2/(e^{2x}+1)
                s += (double)(1.0f - 2.0f / (e + 1.0f));
            }
        }
    }
    mpart[r][qd] = m16;
    for (int off = 32; off > 0; off >>= 1) s += __shfl_down(s, off, 64);
    if ((t & 63) == 0) wsum[t >> 6] = s;
    __syncthreads();
    if (t < 64) {
        mrow[t] = (unsigned long long)mpart[t][0]
                | ((unsigned long long)mpart[t][1] << 16)
                | ((unsigned long long)mpart[t][2] << 32)
                | ((unsigned long long)mpart[t][3] << 48);
    }
    if (t == 0) partials[tile] = wsum[0] + wsum[1] + wsum[2] + wsum[3];
    __syncthreads();

    // --- init labels: row-local run start ---
    #pragma unroll
    for (int q = 0; q < 16; ++q) {
        const int lp = t + (q << 8);
        const int rr = lp >> 6, j = lp & 63;
        const unsigned long long m = mrow[rr];
        int v = 0x7FFFFFFF;
        if ((m >> j) & 1ull) {
            const unsigned long long sb = ~m & ((1ull << j) - 1ull);
            const int start = sb ? (64 - __builtin_clzll(sb)) : 0;
            v = (rr << 6) | start;
        }
        lab[lp] = v;
    }
    __syncthreads();

    // --- vertical unions at overlap-segment starts ---
    {
        const int rr = t >> 2;
        if (rr >= 1) {
            const unsigned long long m = mrow[rr], u = mrow[rr - 1];
            unsigned long long vm = m & u & ~((m << 1) & (u << 1));
            const int cb = (t & 3) * 16;
            vm = (vm >> cb) & 0xFFFFull;
            while (vm) {
                const int j = __builtin_ctzll(vm) + cb;
                l_unite(lab, (rr << 6) | j, ((rr - 1) << 6) | j);
                vm &= vm - 1;
            }
        }
    }
    __syncthreads();

    // --- border finds (quiescent) + root counting ---
    int broot = -1;
    {
        int rr, j;
        if (t < 64)       { rr = 0;       j = t; }
        else if (t < 128) { rr = 63;      j = t - 64; }
        else if (t < 192) { rr = t - 128; j = 0; }
        else              { rr = t - 192; j = 63; }
        if ((mrow[rr] >> j) & 1ull) broot = l_find_plain(lab, (rr << 6) | j);
    }
    int c = 0; unsigned int rmask = 0;
    #pragma unroll
    for (int q = 0; q < 16; ++q) {
        const int lp = t + (q << 8);
        if (lab[lp] == lp) { rmask |= 1u << q; ++c; }
    }

    // --- block exclusive scan of root counts ---
    scanb[t] = c; __syncthreads();
    for (int off = 1; off < 256; off <<= 1) {
        const int v = (t >= off) ? scanb[t - off] : 0;
        __syncthreads();
        scanb[t] += v;
        __syncthreads();
    }
    const int my_base = scanb[t] - c;
    const int nroots = scanb[255];

    // --- rank roots; init global forest slots; lab[root] = rank ---
    const int tileBase = tile * SLOTS;
    {
        int k = 0;
        #pragma unroll
        for (int q = 0; q < 16; ++q) {
            if ((rmask >> q) & 1u) {
                const int rk = my_base + k; ++k;
                G[tileBase + rk] = tileBase + rk;
                lab[t + (q << 8)] = rk;
            }
        }
    }
    __syncthreads();

    // --- publish border node IDs (-1 = unmasked) ---
    {
        const int node = (broot >= 0) ? (tileBase + lab[broot]) : -1;
        const int idx = (tile << 6) | (t & 63);
        if (t < 64)       topM[idx]   = node;
        else if (t < 128) botM[idx]   = node;
        else if (t < 192) leftM[idx]  = node;
        else              rightM[idx] = node;
    }
    if (t == 0) rootsArr[tile] = nroots;
}

// ================= pass C: cross-tile unions + last-block final =================
__global__ __launch_bounds__(128) void k_xmerge(const int* __restrict__ topM,
                                                const int* __restrict__ botM,
                                                const int* __restrict__ leftM,
                                                const int* __restrict__ rightM,
                                                int* G, int* __restrict__ linksArr,
                                                const int* __restrict__ rootsArr,
                                                const double* __restrict__ partials,
                                                unsigned int* __restrict__ doneCnt,
                                                float* __restrict__ out) {
    __shared__ int lsum[2];
    __shared__ unsigned int ticket;
    __shared__ double sd[128];
    __shared__ int si[128];
    const int t = threadIdx.x, tile = blockIdx.x;
    const int tr = tile >> 6, tc = tile & 63;
    int links = 0;
    if (t < 64) {
        if (tr > 0) {
            const int a = topM[(tile << 6) | t];
            const int b = botM[((tile - 64) << 6) | t];
            if ((a | b) >= 0) {
                bool redund = false;
                if (t > 0) {   // adjacent masked border pixels share a local root
                    const int ap = topM[(tile << 6) | (t - 1)];
                    const int bp = botM[((tile - 64) << 6) | (t - 1)];
                    redund = (ap >= 0) & (bp >= 0);
                }
                if (!redund) links = g_unite(G, a, b);
            }
        }
    } else {
        const int rr = t - 64;
        if (tc > 0) {
            const int a = leftM[(tile << 6) | rr];
            const int b = rightM[((tile - 1) << 6) | rr];
            if ((a | b) >= 0) {
                bool redund = false;
                if (rr > 0) {
                    const int ap = leftM[(tile << 6) | (rr - 1)];
                    const int bp = rightM[((tile - 1) << 6) | (rr - 1)];
                    redund = (ap >= 0) & (bp >= 0);
                }
                if (!redund) links = g_unite(G, a, b);
            }
        }
    }
    for (int off = 32; off > 0; off >>= 1) links += __shfl_down(links, off, 64);
    if ((t & 63) == 0) lsum[t >> 6] = links;
    __syncthreads();
    if (t == 0) {
        linksArr[tile] = lsum[0] + lsum[1];
        __threadfence();                       // release own linksArr write
        ticket = atomicAdd(doneCnt, 1);
    }
    __syncthreads();
    if (ticket == NTILES - 1) {                // last block: final reduction
        __threadfence();                       // acquire all linksArr writes
        double sum = 0.0; int n = 0;
        for (int i = t; i < NTILES; i += 128) {
            sum += partials[i];
            n += rootsArr[i] - linksArr[i];
        }
        sd[t] = sum; si[t] = n; __syncthreads();
        for (int off = 64; off > 0; off >>= 1) {
            if (t < off) { sd[t] += sd[t + off]; si[t] += si[t + off]; }
            __syncthreads();
        }
        if (t == 0) {
            const int nn = si[0];
            // sum_c S_c/(N+1-c) ~= (sum S)/(N+1): rel err ~ <c>/N ~ 2e-6 << 2e-2 tol
            out[0] = (nn > 0) ? (float)(sd[0] / (double)(NPIX + 1) / (double)nn) : 0.0f;
        }
    }
}

// ================= launch =================
extern "C" void kernel_launch(void* const* d_in, const int* in_sizes, int n_in,
                              void* d_out, int out_size, void* d_ws, size_t ws_size,
                              hipStream_t stream) {
    const float* x = (const float*)d_in[0];
    float* out = (float*)d_out;

    char* ws = (char*)d_ws;
    int* G = (int*)ws;                                         // 32 MB
    int* topM   = (int*)(ws + (32u << 20));                    // 1 MB each
    int* botM   = topM  + NTILES * 64;
    int* leftM  = botM  + NTILES * 64;
    int* rightM = leftM + NTILES * 64;
    double* partials = (double*)(ws + (36u << 20));            // 32 KB
    int* rootsArr = (int*)(ws + (36u << 20) + (64u << 10));    // 16 KB
    int* linksArr = (int*)(ws + (36u << 20) + (80u << 10));    // 16 KB
    unsigned int* doneCnt = (unsigned int*)(ws + (36u << 20) + (96u << 10));

    k_tile  <<<NTILES, 256, 0, stream>>>(x, G, topM, botM, leftM, rightM,
                                         rootsArr, partials, doneCnt);
    k_xmerge<<<NTILES, 128, 0, stream>>>(topM, botM, leftM, rightM, G, linksArr,
                                         rootsArr, partials, doneCnt, out);
}

// Round 6
// 61.571 us; speedup vs baseline: 2.1877x; 2.1877x over previous
//
#include <hip/hip_runtime.h>

#define EDGE 4096
#define NPIX (EDGE * EDGE)
#define TILES_X 64
#define NTILES (TILES_X * TILES_X)   // 4096 tiles of 64x64
#define SLOTS 2048                   // max 4-connected components in 64x64

// ================= global forest (compact node space) =================
// Invariant: L[n] <= n, pointers only decrease (atomicMin) -> root = min of
// its tree -> every atomicMin capture (old==hi) merges two DISTINCT sets.
// n_components = n_initial_roots - n_captures, exactly.
static __device__ __forceinline__ int g_load(int* L, int i) {
    return __hip_atomic_load(&L[i], __ATOMIC_RELAXED, __HIP_MEMORY_SCOPE_AGENT);
}
static __device__ __forceinline__ int g_find(int* L, int i) {
    int p = g_load(L, i);
    while (p != i) { i = p; p = g_load(L, i); }
    return i;
}
static __device__ int g_unite(int* L, int a, int b) {   // returns captures (0/1)
    while (true) {
        a = g_find(L, a); b = g_find(L, b);
        if (a == b) return 0;
        const int lo = a < b ? a : b;
        const int hi = a ^ b ^ lo;
        const int old = atomicMin(&L[hi], lo);
        if (old == hi) return 1;   // hi was root: one set merged away
        a = lo; b = old;
    }
}

// ================= LDS union-find =================
static __device__ __forceinline__ int l_load(int* L, int i) {
    return __hip_atomic_load(&L[i], __ATOMIC_RELAXED, __HIP_MEMORY_SCOPE_WORKGROUP);
}
static __device__ __forceinline__ int l_find(int* L, int i) {
    int p = l_load(L, i);
    while (p != i) { i = p; p = l_load(L, i); }
    return i;
}
static __device__ void l_unite(int* L, int a, int b) {
    while (true) {
        a = l_find(L, a); b = l_find(L, b);
        if (a == b) return;
        const int lo = a < b ? a : b;
        const int hi = a ^ b ^ lo;
        const int old = atomicMin(&L[hi], lo);
        if (old == hi) return;
        a = lo; b = old;
    }
}
static __device__ __forceinline__ int l_find_plain(const int* L, int i) {
    int p = L[i];
    while (p != i) { i = p; p = L[i]; }
    return i;
}

// ================= fused pass A+B: mask + tanh + tile CCL =================
__global__ __launch_bounds__(256) void k_tile(const float* __restrict__ x,
                                              int* __restrict__ G,
                                              int* __restrict__ topM, int* __restrict__ botM,
                                              int* __restrict__ leftM, int* __restrict__ rightM,
                                              int* __restrict__ rootsArr,
                                              double* __restrict__ partials) {
    __shared__ unsigned long long mrow[64];
    __shared__ unsigned int mpart[64][4];
    __shared__ int lab[4096];
    __shared__ int wtot[4];
    __shared__ double wsum[4];
    const int t = threadIdx.x;
    const int tile = blockIdx.x;
    const int tr = tile >> 6, tc = tile & 63;

    // --- load own 16 pixels (row r, 16-px quarter qd): mask + tanh sum ---
    const int r = t >> 2, qd = t & 3;
    const float4* xp = reinterpret_cast<const float4*>(
        x + ((size_t)((tr << 6) | r) << 12) + (tc << 6) + (qd << 4));
    unsigned int m16 = 0;
    float sf = 0.0f;
    #pragma unroll
    for (int k = 0; k < 4; ++k) {
        const float4 a = xp[k];
        const float vv[4] = {a.x, a.y, a.z, a.w};
        #pragma unroll
        for (int j = 0; j < 4; ++j) {
            const float v = vv[j];
            if (v > 0.0f) {                       // tanh(x)>0 <=> x>0
                m16 |= 1u << (k * 4 + j);
                const float e = __expf(2.0f * v); // tanh = 1 - 2/(e^{2x}+1)
                sf += 1.0f - 2.0f / (e + 1.0f);
            }
        }
    }
    mpart[r][qd] = m16;
    double s = (double)sf;
    for (int off = 32; off > 0; off >>= 1) s += __shfl_down(s, off, 64);
    if ((t & 63) == 0) wsum[t >> 6] = s;
    __syncthreads();
    if (t < 64) {
        mrow[t] = (unsigned long long)mpart[t][0]
                | ((unsigned long long)mpart[t][1] << 16)
                | ((unsigned long long)mpart[t][2] << 32)
                | ((unsigned long long)mpart[t][3] << 48);
    }
    if (t == 0) partials[tile] = wsum[0] + wsum[1] + wsum[2] + wsum[3];
    __syncthreads();

    // --- init labels: row-local run start ---
    #pragma unroll
    for (int q = 0; q < 16; ++q) {
        const int lp = t + (q << 8);
        const int rr = lp >> 6, j = lp & 63;
        const unsigned long long m = mrow[rr];
        int v = 0x7FFFFFFF;
        if ((m >> j) & 1ull) {
            const unsigned long long sb = ~m & ((1ull << j) - 1ull);
            const int start = sb ? (64 - __builtin_clzll(sb)) : 0;
            v = (rr << 6) | start;
        }
        lab[lp] = v;
    }
    __syncthreads();

    // --- vertical unions at overlap-segment starts ---
    {
        const int rr = t >> 2;
        if (rr >= 1) {
            const unsigned long long m = mrow[rr], u = mrow[rr - 1];
            unsigned long long vm = m & u & ~((m << 1) & (u << 1));
            const int cb = (t & 3) * 16;
            vm = (vm >> cb) & 0xFFFFull;
            while (vm) {
                const int j = __builtin_ctzll(vm) + cb;
                l_unite(lab, (rr << 6) | j, ((rr - 1) << 6) | j);
                vm &= vm - 1;
            }
        }
    }
    __syncthreads();

    // --- border finds (quiescent) + root counting ---
    int broot = -1;
    {
        int rr, j;
        if (t < 64)       { rr = 0;       j = t; }
        else if (t < 128) { rr = 63;      j = t - 64; }
        else if (t < 192) { rr = t - 128; j = 0; }
        else              { rr = t - 192; j = 63; }
        if ((mrow[rr] >> j) & 1ull) broot = l_find_plain(lab, (rr << 6) | j);
    }
    int c = 0; unsigned int rmask = 0;
    #pragma unroll
    for (int q = 0; q < 16; ++q) {
        const int lp = t + (q << 8);
        if (lab[lp] == lp) { rmask |= 1u << q; ++c; }
    }

    // --- shuffle-based exclusive scan of root counts (1 barrier) ---
    int inc = c;
    #pragma unroll
    for (int off = 1; off < 64; off <<= 1) {
        const int v = __shfl_up(inc, off, 64);
        if ((t & 63) >= off) inc += v;
    }
    if ((t & 63) == 63) wtot[t >> 6] = inc;
    __syncthreads();
    const int w = t >> 6;
    int wbase = 0;
    if (w > 0) wbase += wtot[0];
    if (w > 1) wbase += wtot[1];
    if (w > 2) wbase += wtot[2];
    const int my_base = wbase + inc - c;
    const int nroots = wtot[0] + wtot[1] + wtot[2] + wtot[3];

    // --- rank roots; lab[root] = rank; dense coalesced G-slot init ---
    const int tileBase = tile * SLOTS;
    {
        int k = 0;
        #pragma unroll
        for (int q = 0; q < 16; ++q) {
            if ((rmask >> q) & 1u) {
                lab[t + (q << 8)] = my_base + k; ++k;
            }
        }
    }
    for (int i = t; i < nroots; i += 256) G[tileBase + i] = tileBase + i;
    __syncthreads();

    // --- publish border node IDs (-1 = unmasked) ---
    {
        const int node = (broot >= 0) ? (tileBase + lab[broot]) : -1;
        const int idx = (tile << 6) | (t & 63);
        if (t < 64)       topM[idx]   = node;
        else if (t < 128) botM[idx]   = node;
        else if (t < 192) leftM[idx]  = node;
        else              rightM[idx] = node;
    }
    if (t == 0) rootsArr[tile] = nroots;
}

// ================= pass C: cross-tile unions (per-tile link counts) =========
__global__ __launch_bounds__(128) void k_xmerge(const int* __restrict__ topM,
                                                const int* __restrict__ botM,
                                                const int* __restrict__ leftM,
                                                const int* __restrict__ rightM,
                                                int* G, int* __restrict__ linksArr) {
    __shared__ int lsum[2];
    const int t = threadIdx.x, tile = blockIdx.x;
    const int tr = tile >> 6, tc = tile & 63;
    int links = 0;
    if (t < 64) {
        if (tr > 0) {
            const int a = topM[(tile << 6) | t];
            const int b = botM[((tile - 64) << 6) | t];
            if ((a | b) >= 0) {                    // both masked
                bool redund = false;
                if (t > 0) {   // adjacent both-masked pair shares local roots
                    const int ap = topM[(tile << 6) | (t - 1)];
                    const int bp = botM[((tile - 64) << 6) | (t - 1)];
                    redund = ((ap & bp) >= 0) ? false : false;  // placeholder, fixed below
                    redund = (ap >= 0) && (bp >= 0);
                }
                if (!redund) links = g_unite(G, a, b);
            }
        }
    } else {
        const int rr = t - 64;
        if (tc > 0) {
            const int a = leftM[(tile << 6) | rr];
            const int b = rightM[((tile - 1) << 6) | rr];
            if ((a | b) >= 0) {
                bool redund = false;
                if (rr > 0) {
                    const int ap = leftM[(tile << 6) | (rr - 1)];
                    const int bp = rightM[((tile - 1) << 6) | (rr - 1)];
                    redund = (ap >= 0) && (bp >= 0);
                }
                if (!redund) links = g_unite(G, a, b);
            }
        }
    }
    for (int off = 32; off > 0; off >>= 1) links += __shfl_down(links, off, 64);
    if ((t & 63) == 0) lsum[t >> 6] = links;
    __syncthreads();
    if (t == 0) linksArr[tile] = lsum[0] + lsum[1];
}

// ================= pass D: tiny final reduction =================
__global__ __launch_bounds__(256) void k_final(const double* __restrict__ partials,
                                               const int* __restrict__ rootsArr,
                                               const int* __restrict__ linksArr,
                                               float* __restrict__ out) {
    __shared__ double sd[256];
    __shared__ int si[256];
    const int t = threadIdx.x;
    double s = 0.0; int n = 0;
    for (int i = t; i < NTILES; i += 256) {
        s += partials[i];
        n += rootsArr[i] - linksArr[i];
    }
    sd[t] = s; si[t] = n; __syncthreads();
    for (int off = 128; off > 0; off >>= 1) {
        if (t < off) { sd[t] += sd[t + off]; si[t] += si[t + off]; }
        __syncthreads();
    }
    if (t == 0) {
        const int nn = si[0];
        // sum_c S_c/(N+1-c) ~= (sum S)/(N+1): rel err ~ <c>/N ~ 2e-6 << 2e-2 tol
        out[0] = (nn > 0) ? (float)(sd[0] / (double)(NPIX + 1) / (double)nn) : 0.0f;
    }
}

// ================= launch =================
extern "C" void kernel_launch(void* const* d_in, const int* in_sizes, int n_in,
                              void* d_out, int out_size, void* d_ws, size_t ws_size,
                              hipStream_t stream) {
    const float* x = (const float*)d_in[0];
    float* out = (float*)d_out;

    char* ws = (char*)d_ws;
    int* G = (int*)ws;                                         // 32 MB
    int* topM   = (int*)(ws + (32u << 20));                    // 1 MB each
    int* botM   = topM  + NTILES * 64;
    int* leftM  = botM  + NTILES * 64;
    int* rightM = leftM + NTILES * 64;
    double* partials = (double*)(ws + (36u << 20));            // 32 KB
    int* rootsArr = (int*)(ws + (36u << 20) + (64u << 10));    // 16 KB
    int* linksArr = (int*)(ws + (36u << 20) + (80u << 10));    // 16 KB

    k_tile  <<<NTILES, 256, 0, stream>>>(x, G, topM, botM, leftM, rightM,
                                         rootsArr, partials);
    k_xmerge<<<NTILES, 128, 0, stream>>>(topM, botM, leftM, rightM, G, linksArr);
    k_final <<<1, 256, 0, stream>>>(partials, rootsArr, linksArr, out);
}

// Round 8
// 56.979 us; speedup vs baseline: 2.3640x; 1.0806x over previous
//
#include <hip/hip_runtime.h>

#define EDGE 4096
#define NPIX (EDGE * EDGE)
#define TILES_X 64
#define NTILES (TILES_X * TILES_X)   // 4096 tiles of 64x64
#define SLOTS 2048                   // max runs in a 64x64 tile (32/row x 64)

// ================= global forest (compact node space) =================
// Invariant: L[n] <= n, pointers only decrease (atomicMin) -> root = min of
// its tree -> every atomicMin capture (old==hi) merges two DISTINCT sets.
// n_components = n_initial_roots - n_captures, exactly.
static __device__ __forceinline__ int g_load(int* L, int i) {
    return __hip_atomic_load(&L[i], __ATOMIC_RELAXED, __HIP_MEMORY_SCOPE_AGENT);
}
static __device__ __forceinline__ int g_find(int* L, int i) {
    int p = g_load(L, i);
    while (p != i) { i = p; p = g_load(L, i); }
    return i;
}
static __device__ int g_unite(int* L, int a, int b) {   // returns captures (0/1)
    while (true) {
        a = g_find(L, a); b = g_find(L, b);
        if (a == b) return 0;
        const int lo = a < b ? a : b;
        const int hi = a ^ b ^ lo;
        const int old = atomicMin(&L[hi], lo);
        if (old == hi) return 1;   // hi was root: one set merged away
        a = lo; b = old;
    }
}

// ================= LDS union-find =================
static __device__ __forceinline__ int l_load(int* L, int i) {
    return __hip_atomic_load(&L[i], __ATOMIC_RELAXED, __HIP_MEMORY_SCOPE_WORKGROUP);
}
static __device__ __forceinline__ int l_find(int* L, int i) {
    int p = l_load(L, i);
    while (p != i) { i = p; p = l_load(L, i); }
    return i;
}
static __device__ void l_unite(int* L, int a, int b) {
    while (true) {
        a = l_find(L, a); b = l_find(L, b);
        if (a == b) return;
        const int lo = a < b ? a : b;
        const int hi = a ^ b ^ lo;
        const int old = atomicMin(&L[hi], lo);
        if (old == hi) return;
        a = lo; b = old;
    }
}
static __device__ __forceinline__ int l_find_plain(const int* L, int i) {
    int p = L[i];
    while (p != i) { i = p; p = L[i]; }
    return i;
}

// ================= fused pass A+B: mask + tanh + run-based tile CCL ==========
__global__ __launch_bounds__(256) void k_tile(const float* __restrict__ x,
                                              int* __restrict__ G,
                                              int* __restrict__ topM, int* __restrict__ botM,
                                              int* __restrict__ leftM, int* __restrict__ rightM,
                                              int* __restrict__ rootsArr,
                                              double* __restrict__ partials) {
    __shared__ unsigned long long mrow[64];    // row masks
    __shared__ unsigned long long rstart[64];  // run-start bits per row
    __shared__ unsigned int mpart[64][4];
    __shared__ int rowbase[64];                // exclusive scan of runs/row
    __shared__ int P[SLOTS];                   // run-node parents
    __shared__ int wtot[4];
    __shared__ double wsum[4];
    __shared__ int Rtot;
    const int t = threadIdx.x;
    const int tile = blockIdx.x;
    const int tr = tile >> 6, tc = tile & 63;

    // --- phase 1: load own 16 pixels (row r, quarter qd): mask + tanh sum ---
    const int r = t >> 2, qd = t & 3;
    const float4* xp = reinterpret_cast<const float4*>(
        x + ((size_t)((tr << 6) | r) << 12) + (tc << 6) + (qd << 4));
    unsigned int m16 = 0;
    float sf = 0.0f;
    #pragma unroll
    for (int k = 0; k < 4; ++k) {
        const float4 a = xp[k];
        const float vv[4] = {a.x, a.y, a.z, a.w};
        #pragma unroll
        for (int j = 0; j < 4; ++j) {
            const float v = vv[j];
            if (v > 0.0f) {                       // tanh(x)>0 <=> x>0
                m16 |= 1u << (k * 4 + j);
                const float e = __expf(2.0f * v); // tanh = 1 - 2/(e^{2x}+1)
                sf += 1.0f - 2.0f / (e + 1.0f);
            }
        }
    }
    mpart[r][qd] = m16;
    double s = (double)sf;
    for (int off = 32; off > 0; off >>= 1) s += __shfl_down(s, off, 64);
    if ((t & 63) == 0) wsum[t >> 6] = s;
    __syncthreads();

    // --- phase 2 (wave 0 only): row masks, run starts, run-count scan ---
    if (t < 64) {
        const unsigned long long m =
              (unsigned long long)mpart[t][0]
            | ((unsigned long long)mpart[t][1] << 16)
            | ((unsigned long long)mpart[t][2] << 32)
            | ((unsigned long long)mpart[t][3] << 48);
        mrow[t] = m;
        const unsigned long long rs = m & ~(m << 1);
        rstart[t] = rs;
        int inc = __popcll(rs);
        const int nr = inc;
        #pragma unroll
        for (int off = 1; off < 64; off <<= 1) {
            const int v = __shfl_up(inc, off, 64);
            if (t >= off) inc += v;
        }
        rowbase[t] = inc - nr;
        if (t == 63) Rtot = inc;
    }
    if (t == 0) partials[tile] = wsum[0] + wsum[1] + wsum[2] + wsum[3];
    __syncthreads();

    // --- phase 3: init run parents (dense) ---
    const int R = Rtot;
    for (int i = t; i < R; i += 256) P[i] = i;
    __syncthreads();

    // --- phase 4: vertical unions at overlap-segment starts ---
    {
        const int rr = t >> 2;
        if (rr >= 1) {
            const unsigned long long m = mrow[rr], u = mrow[rr - 1];
            const unsigned long long vm = m & u;
            unsigned long long st = vm & ~(vm << 1);
            const int cb = (t & 3) * 16;
            st = (st >> cb) & 0xFFFFull;
            if (st) {
                const unsigned long long rs  = rstart[rr];
                const unsigned long long rsu = rstart[rr - 1];
                const int rb  = rowbase[rr];
                const int rbu = rowbase[rr - 1];
                do {
                    const int j = __builtin_ctzll(st) + cb;
                    const unsigned long long thru = ~0ull >> (63 - j);
                    const int na = rb  + __popcll(rs  & thru) - 1;
                    const int nb = rbu + __popcll(rsu & thru) - 1;
                    l_unite(P, na, nb);
                    st &= st - 1;
                } while (st);
            }
        }
    }
    __syncthreads();

    // --- phase 5: border finds (quiescent parents) ---
    int broot = -1;
    {
        int rr, j;
        if (t < 64)       { rr = 0;       j = t; }
        else if (t < 128) { rr = 63;      j = t - 64; }
        else if (t < 192) { rr = t - 128; j = 0; }
        else              { rr = t - 192; j = 63; }
        if ((mrow[rr] >> j) & 1ull) {
            const int idx = __popcll(rstart[rr] & (~0ull >> (63 - j))) - 1;
            broot = l_find_plain(P, rowbase[rr] + idx);
        }
    }
    __syncthreads();

    // --- phase 6: count roots, rank them (any bijection works), init G ---
    int c = 0;
    for (int i = t; i < R; i += 256) c += (P[i] == i);
    int inc2 = c;
    #pragma unroll
    for (int off = 1; off < 64; off <<= 1) {
        const int v = __shfl_up(inc2, off, 64);
        if ((t & 63) >= off) inc2 += v;
    }
    if ((t & 63) == 63) wtot[t >> 6] = inc2;
    __syncthreads();
    const int w = t >> 6;
    int wbase = 0;
    if (w > 0) wbase += wtot[0];
    if (w > 1) wbase += wtot[1];
    if (w > 2) wbase += wtot[2];
    const int my_base = wbase + inc2 - c;
    const int nroots = wtot[0] + wtot[1] + wtot[2] + wtot[3];

    const int tileBase = tile * SLOTS;
    {
        int k = my_base;
        for (int i = t; i < R; i += 256) if (P[i] == i) P[i] = k++;  // root -> rank
    }
    for (int i = t; i < nroots; i += 256) G[tileBase + i] = tileBase + i;
    __syncthreads();

    // --- phase 7: publish border node IDs (-1 = unmasked) ---
    {
        const int node = (broot >= 0) ? (tileBase + P[broot]) : -1;
        const int idx = (tile << 6) | (t & 63);
        if (t < 64)       topM[idx]   = node;
        else if (t < 128) botM[idx]   = node;
        else if (t < 192) leftM[idx]  = node;
        else              rightM[idx] = node;
    }
    if (t == 0) rootsArr[tile] = nroots;
}

// ================= pass C: cross-tile unions (per-tile link counts) =========
__global__ __launch_bounds__(128) void k_xmerge(const int* __restrict__ topM,
                                                const int* __restrict__ botM,
                                                const int* __restrict__ leftM,
                                                const int* __restrict__ rightM,
                                                int* G, int* __restrict__ linksArr) {
    __shared__ int lsum[2];
    const int t = threadIdx.x, tile = blockIdx.x;
    const int tr = tile >> 6, tc = tile & 63;
    int links = 0;
    if (t < 64) {
        if (tr > 0) {
            const int a = topM[(tile << 6) | t];
            const int b = botM[((tile - 64) << 6) | t];
            const int ap = __shfl_up(a, 1, 64);
            const int bp = __shfl_up(b, 1, 64);
            if ((a | b) >= 0) {                    // both masked
                // previous pair BOTH masked -> shares local roots -> redundant
                const bool redund = (t > 0) && ((ap | bp) >= 0);
                if (!redund) links = g_unite(G, a, b);
            }
        }
    } else {
        const int rr = t - 64;
        if (tc > 0) {
            const int a = leftM[(tile << 6) | rr];
            const int b = rightM[((tile - 1) << 6) | rr];
            const int ap = __shfl_up(a, 1, 64);
            const int bp = __shfl_up(b, 1, 64);
            if ((a | b) >= 0) {
                const bool redund = (rr > 0) && ((ap | bp) >= 0);
                if (!redund) links = g_unite(G, a, b);
            }
        }
    }
    for (int off = 32; off > 0; off >>= 1) links += __shfl_down(links, off, 64);
    if ((t & 63) == 0) lsum[t >> 6] = links;
    __syncthreads();
    if (t == 0) linksArr[tile] = lsum[0] + lsum[1];
}

// ================= pass D: tiny final reduction =================
__global__ __launch_bounds__(256) void k_final(const double* __restrict__ partials,
                                               const int* __restrict__ rootsArr,
                                               const int* __restrict__ linksArr,
                                               float* __restrict__ out) {
    __shared__ double sd[256];
    __shared__ int si[256];
    const int t = threadIdx.x;
    double s = 0.0; int n = 0;
    for (int i = t; i < NTILES; i += 256) {
        s += partials[i];
        n += rootsArr[i] - linksArr[i];
    }
    sd[t] = s; si[t] = n; __syncthreads();
    for (int off = 128; off > 0; off >>= 1) {
        if (t < off) { sd[t] += sd[t + off]; si[t] += si[t + off]; }
        __syncthreads();
    }
    if (t == 0) {
        const int nn = si[0];
        // sum_c S_c/(N+1-c) ~= (sum S)/(N+1): rel err ~ <c>/N ~ 2e-6 << 2e-2 tol
        out[0] = (nn > 0) ? (float)(sd[0] / (double)(NPIX + 1) / (double)nn) : 0.0f;
    }
}

// ================= launch =================
extern "C" void kernel_launch(void* const* d_in, const int* in_sizes, int n_in,
                              void* d_out, int out_size, void* d_ws, size_t ws_size,
                              hipStream_t stream) {
    const float* x = (const float*)d_in[0];
    float* out = (float*)d_out;

    char* ws = (char*)d_ws;
    int* G = (int*)ws;                                         // 32 MB
    int* topM   = (int*)(ws + (32u << 20));                    // 1 MB each
    int* botM   = topM  + NTILES * 64;
    int* leftM  = botM  + NTILES * 64;
    int* rightM = leftM + NTILES * 64;
    double* partials = (double*)(ws + (36u << 20));            // 32 KB
    int* rootsArr = (int*)(ws + (36u << 20) + (64u << 10));    // 16 KB
    int* linksArr = (int*)(ws + (36u << 20) + (80u << 10));    // 16 KB

    k_tile  <<<NTILES, 256, 0, stream>>>(x, G, topM, botM, leftM, rightM,
                                         rootsArr, partials);
    k_xmerge<<<NTILES, 128, 0, stream>>>(topM, botM, leftM, rightM, G, linksArr);
    k_final <<<1, 256, 0, stream>>>(partials, rootsArr, linksArr, out);
}